// Round 1
// baseline (781.100 us; speedup 1.0000x reference)
//
#include <hip/hip_runtime.h>

typedef float  f32x4  __attribute__((ext_vector_type(4)));
typedef short  bf16x8 __attribute__((ext_vector_type(8)));
typedef short  s16x4  __attribute__((ext_vector_type(4)));

__device__ __forceinline__ unsigned short f2bf(float f) {
    unsigned int u = __float_as_uint(f);
    unsigned int r = (u + 0x7FFFu + ((u >> 16) & 1u)) >> 16;
    return (unsigned short)r;
}
__device__ __forceinline__ float bf2f(unsigned short h) {
    return __uint_as_float(((unsigned int)h) << 16);
}

// ---------------------------------------------------------------------------
// K1: transpose x -> xT[p][n][pos][c] (bf16, channel-last) + t-means (atomic)
// grid: 2*32*32 blocks (p, n, tc of 8 t's = 200 pos), 256 threads
// ---------------------------------------------------------------------------
__global__ void k1_transpose_mean(const float* __restrict__ x1,
                                  const float* __restrict__ x2,
                                  float* __restrict__ xm,
                                  unsigned short* __restrict__ xT)
{
    const int b  = blockIdx.x;
    const int p  = b >> 10;
    const int n  = (b >> 5) & 31;
    const int tc = b & 31;
    const float* __restrict__ x = p ? x2 : x1;

    __shared__ float tile[64 * 201];   // padded stride 201 to break bank conflicts
    const int tid = threadIdx.x;
    const size_t xbase = (size_t)n * 64 * 6400 + (size_t)tc * 200;

    for (int idx = tid; idx < 3200; idx += 256) {
        const int c = idx / 50, qq = idx % 50;
        const f32x4 v = *(const f32x4*)(x + xbase + (size_t)c * 6400 + qq * 4);
        tile[c * 201 + qq * 4 + 0] = v[0];
        tile[c * 201 + qq * 4 + 1] = v[1];
        tile[c * 201 + qq * 4 + 2] = v[2];
        tile[c * 201 + qq * 4 + 3] = v[3];
    }
    __syncthreads();

    // partial means over this block's 8 t's
    for (int idx = tid; idx < 1600; idx += 256) {
        const int c = idx / 25, v = idx % 25;
        float s = 0.f;
        #pragma unroll
        for (int tt = 0; tt < 8; tt++) s += tile[c * 201 + tt * 25 + v];
        atomicAdd(&xm[((size_t)(p * 32 + n) * 64 + c) * 25 + v], s * (1.0f / 256.0f));
    }

    // transposed bf16 write: xT[(p,n)][pos][c], lanes cover 4 c's x 4 pos
    const int pg = tid >> 4;          // 0..15
    const int c4 = (tid & 15) * 4;    // 0,4,...,60
    for (int p0 = 0; p0 < 13; p0++) {
        const int pos = p0 * 16 + pg;
        if (pos < 200) {
            s16x4 o;
            #pragma unroll
            for (int k = 0; k < 4; k++) o[k] = (short)f2bf(tile[(c4 + k) * 201 + pos]);
            *(s16x4*)(xT + (((size_t)(p * 32 + n) * 6400 + tc * 200 + pos) * 64 + c4)) = o;
        }
    }
}

// ---------------------------------------------------------------------------
// K2: r1/r2 -> rel -> a1/a2 packed as MFMA B-fragments (bf16, zero-padded)
// grid: 96 blocks (i, n), 256 threads
// aw layout: [p][i][n][c][ut(2)][lane(64)][j(8)]  (halfwords)
// ---------------------------------------------------------------------------
__global__ void k2_adj(const float* __restrict__ xm,
                       const float* __restrict__ PA, const float* __restrict__ alpha,
                       const float* __restrict__ c1w, const float* __restrict__ c1b,
                       const float* __restrict__ c2w, const float* __restrict__ c2b,
                       const float* __restrict__ c5w, const float* __restrict__ c5b,
                       const float* __restrict__ c6w, const float* __restrict__ c6b,
                       unsigned short* __restrict__ aw)
{
    const int b = blockIdx.x;
    const int i = b >> 5;
    const int n = b & 31;
    __shared__ float xml[3200];
    __shared__ float rl[400];
    __shared__ float rel[5000];
    const int tid = threadIdx.x;

    for (int idx = tid; idx < 3200; idx += 256) {
        const int p_ = idx / 1600, rest = idx % 1600;
        xml[idx] = xm[(size_t)(p_ * 32 + n) * 1600 + rest];
    }
    __syncthreads();

    for (int idx = tid; idx < 400; idx += 256) {
        const int which = idx / 200;
        const int rr = (idx % 200) / 25;
        const int v = idx % 25;
        const float* wv = (which ? c2w : c1w) + (i * 8 + rr) * 64;
        const float* xp = xml + which * 1600;
        float s = (which ? c2b : c1b)[i * 8 + rr];
        for (int c = 0; c < 64; c++) s += wv[c] * xp[c * 25 + v];
        rl[idx] = s;
    }
    __syncthreads();

    for (int idx = tid; idx < 5000; idx += 256) {
        const int r_ = idx / 625;
        const int rem = idx - r_ * 625;
        const int u = rem / 25;
        const int v = rem - u * 25;
        rel[idx] = tanhf(rl[r_ * 25 + u] - rl[200 + r_ * 25 + v]);
    }
    __syncthreads();

    const float al = alpha[0];
    for (int p_ = 0; p_ < 2; p_++) {
        const float* w5 = p_ ? c6w : c5w;
        const float* b5 = p_ ? c6b : c5b;
        for (int idx = tid; idx < 8192; idx += 256) {
            const int c = idx >> 7;
            const int ut = (idx >> 6) & 1;
            const int lane = idx & 63;
            const int u = ut * 16 + (lane & 15);
            const int qd = lane >> 4;
            bf16x8 outv;
            if (u < 25) {
                float wrow[8];
                #pragma unroll
                for (int r = 0; r < 8; r++) wrow[r] = w5[(i * 64 + c) * 8 + r];
                const float bias = b5[i * 64 + c];
                #pragma unroll
                for (int j = 0; j < 8; j++) {
                    const int v = qd * 8 + j;
                    float s = 0.f;
                    if (v < 25) {
                        s = bias + (p_ ? al : PA[i * 625 + u * 25 + v]);
                        #pragma unroll
                        for (int r = 0; r < 8; r++) s += rel[r * 625 + u * 25 + v] * wrow[r];
                    }
                    outv[j] = (short)f2bf(s);
                }
            } else {
                #pragma unroll
                for (int j = 0; j < 8; j++) outv[j] = 0;
            }
            *(bf16x8*)(aw + ((size_t)((p_ * 3 + i) * 32 + n) * 64 + c) * 1024
                          + ut * 512 + lane * 8) = outv;
        }
    }
}

// ---------------------------------------------------------------------------
// K3: fused conv(MFMA) -> per-channel adjacency matmul(MFMA) -> z (bf16) + stats
// grid: 2*32*16 blocks (p, n, tc of 16 t's = 400 pos), 256 threads (4 waves)
// wave w owns channels [16w,16w+16); no __syncthreads needed (private LDS).
// ---------------------------------------------------------------------------
__global__ __launch_bounds__(256, 2) void k3_main(
    const unsigned short* __restrict__ xT,
    const float* __restrict__ c3w, const float* __restrict__ c3b,
    const float* __restrict__ c4w, const float* __restrict__ c4b,
    const unsigned short* __restrict__ aw,
    unsigned short* __restrict__ z,
    float* __restrict__ stats)
{
    const int b  = blockIdx.x;
    const int p  = b >> 9;
    const int n  = (b >> 4) & 31;
    const int tc = b & 15;
    const float* __restrict__ w3 = p ? c4w : c3w;
    const float* __restrict__ b3 = p ? c4b : c3b;

    __shared__ short X3s[32768];   // 64 KiB: [wave][c_loc(16)][t(16)][32 swizzled]
    const int tid  = threadIdx.x;
    const int w    = tid >> 6;
    const int lane = tid & 63;
    const int q    = lane >> 4;
    const int m    = lane & 15;

    {   // zero own region (provides v=25..31 zero padding)
        int* X3i = (int*)X3s;
        for (int k = 0; k < 64; k++) X3i[w * 4096 + k * 64 + lane] = 0;
    }

    f32x4 acc[16][2];
    #pragma unroll
    for (int cl = 0; cl < 16; cl++) {
        acc[cl][0] = (f32x4){0.f, 0.f, 0.f, 0.f};
        acc[cl][1] = (f32x4){0.f, 0.f, 0.f, 0.f};
    }

    const size_t xTbase = ((size_t)(p * 32 + n) * 6400 + (size_t)tc * 400) * 64;
    const int slot2 = q ^ ((m >> 1) & 3);

    for (int i = 0; i < 3; i++) {
        // stage-1 A-fragments: W rows [16w..16w+16), K=64 in two 32-tiles
        const float* wr = w3 + (size_t)(i * 64 + w * 16 + m) * 64;
        bf16x8 af0, af1;
        {
            f32x4 w00 = *(const f32x4*)(wr + q * 8);
            f32x4 w01 = *(const f32x4*)(wr + q * 8 + 4);
            f32x4 w10 = *(const f32x4*)(wr + 32 + q * 8);
            f32x4 w11 = *(const f32x4*)(wr + 32 + q * 8 + 4);
            #pragma unroll
            for (int k = 0; k < 4; k++) {
                af0[k] = (short)f2bf(w00[k]); af0[k + 4] = (short)f2bf(w01[k]);
                af1[k] = (short)f2bf(w10[k]); af1[k + 4] = (short)f2bf(w11[k]);
            }
        }
        float bb[4];
        #pragma unroll
        for (int r = 0; r < 4; r++) bb[r] = b3[i * 64 + w * 16 + q * 4 + r];

        // stage 1: X3 = W3 * X  (B-frags straight from channel-last xT)
        for (int nt = 0; nt < 25; nt++) {
            const int pos = nt * 16 + m;
            const unsigned short* xp = xT + xTbase + (size_t)pos * 64 + q * 8;
            const bf16x8 xb0 = *(const bf16x8*)(xp);
            const bf16x8 xb1 = *(const bf16x8*)(xp + 32);
            f32x4 d = (f32x4){0.f, 0.f, 0.f, 0.f};
            d = __builtin_amdgcn_mfma_f32_16x16x32_bf16(af0, xb0, d, 0, 0, 0);
            d = __builtin_amdgcn_mfma_f32_16x16x32_bf16(af1, xb1, d, 0, 0, 0);
            const int t = pos / 25;
            const int v = pos - t * 25;
            const int slot = (v >> 3) ^ ((t >> 1) & 3);
            const int hw = w * 8192 + t * 32 + slot * 8 + (v & 7);
            #pragma unroll
            for (int r = 0; r < 4; r++)
                X3s[hw + (q * 4 + r) * 512] = (short)f2bf(d[r] + bb[r]);
        }

        // stage 2: per channel, Z[t][u] += X3[t][v] * a[u][v]
        const size_t ab = ((size_t)((p * 3 + i) * 32 + n) * 64 + w * 16) * 1024 + lane * 8;
        #pragma unroll
        for (int cl = 0; cl < 16; cl++) {
            const bf16x8 xa = *(const bf16x8*)(X3s + w * 8192 + cl * 512 + m * 32 + slot2 * 8);
            const bf16x8 ba = *(const bf16x8*)(aw + ab + cl * 1024);
            const bf16x8 bbv = *(const bf16x8*)(aw + ab + cl * 1024 + 512);
            acc[cl][0] = __builtin_amdgcn_mfma_f32_16x16x32_bf16(xa, ba,  acc[cl][0], 0, 0, 0);
            acc[cl][1] = __builtin_amdgcn_mfma_f32_16x16x32_bf16(xa, bbv, acc[cl][1], 0, 0, 0);
        }
    }

    // epilogue: write z (bf16) + per-channel sum/sumsq
    const size_t zb = ((size_t)((p * 32 + n) * 64 + w * 16)) * 6400 + (size_t)tc * 400;
    #pragma unroll
    for (int cl = 0; cl < 16; cl++) {
        float sum = 0.f, ssq = 0.f;
        #pragma unroll
        for (int ut = 0; ut < 2; ut++) {
            const int u = ut * 16 + m;
            if (u < 25) {
                const f32x4 A = acc[cl][ut];
                #pragma unroll
                for (int r = 0; r < 4; r++) {
                    const float val = A[r];
                    sum += val; ssq += val * val;
                    z[zb + cl * 6400 + (q * 4 + r) * 25 + u] = f2bf(val);
                }
            }
        }
        #pragma unroll
        for (int off = 32; off > 0; off >>= 1) {
            sum += __shfl_xor(sum, off, 64);
            ssq += __shfl_xor(ssq, off, 64);
        }
        if (lane == 0) {
            atomicAdd(&stats[(p * 64 + w * 16 + cl) * 2 + 0], sum);
            atomicAdd(&stats[(p * 64 + w * 16 + cl) * 2 + 1], ssq);
        }
    }
}

// ---------------------------------------------------------------------------
// K4: BN stats -> per-channel scale/shift
// ---------------------------------------------------------------------------
__global__ void k4_finalize(const float* __restrict__ stats,
                            const float* __restrict__ bn1w, const float* __restrict__ bn1b,
                            const float* __restrict__ bn2w, const float* __restrict__ bn2b,
                            float* __restrict__ ss)
{
    const int tid = threadIdx.x;
    if (tid < 128) {
        const int p = tid >> 6, c = tid & 63;
        const float cnt = 204800.f;   // N*T*V
        const float mean = stats[tid * 2] / cnt;
        const float var  = stats[tid * 2 + 1] / cnt - mean * mean;
        const float gw = p ? bn2w[c] : bn1w[c];
        const float gb = p ? bn2b[c] : bn1b[c];
        const float scale = gw * rsqrtf(var + 1e-5f);
        ss[tid * 2]     = scale;
        ss[tid * 2 + 1] = gb - mean * scale;
    }
}

// ---------------------------------------------------------------------------
// K5: y = relu(z*scale + shift + x), float4-wide
// ---------------------------------------------------------------------------
__global__ void k5_apply(const float* __restrict__ x1, const float* __restrict__ x2,
                         const unsigned short* __restrict__ z, const float* __restrict__ ss,
                         float* __restrict__ out)
{
    const size_t g = (size_t)blockIdx.x * 256 + threadIdx.x;
    const size_t e = g * 4;
    const int p = (int)(e / 13107200u);
    const int c = (int)((e / 6400u) & 63);
    const float* xsrc = p ? x2 : x1;
    const f32x4 xv = *(const f32x4*)(xsrc + (e - (size_t)p * 13107200u));
    const s16x4 zv = *(const s16x4*)(const void*)(z + e);
    const float scale = ss[(p * 64 + c) * 2];
    const float shift = ss[(p * 64 + c) * 2 + 1];
    f32x4 o;
    #pragma unroll
    for (int k = 0; k < 4; k++) {
        const float zf = bf2f((unsigned short)zv[k]);
        const float y = zf * scale + shift + xv[k];
        o[k] = y > 0.f ? y : 0.f;
    }
    *(f32x4*)(out + e) = o;
}

// ---------------------------------------------------------------------------
extern "C" void kernel_launch(void* const* d_in, const int* in_sizes, int n_in,
                              void* d_out, int out_size, void* d_ws, size_t ws_size,
                              hipStream_t stream)
{
    (void)in_sizes; (void)n_in; (void)out_size; (void)ws_size;
    const float* x1   = (const float*)d_in[0];
    const float* x2   = (const float*)d_in[1];
    const float* PA   = (const float*)d_in[2];
    const float* alp  = (const float*)d_in[3];
    const float* c1w  = (const float*)d_in[4];
    const float* c1b  = (const float*)d_in[5];
    const float* c2w  = (const float*)d_in[6];
    const float* c2b  = (const float*)d_in[7];
    const float* c3w  = (const float*)d_in[8];
    const float* c3b  = (const float*)d_in[9];
    const float* c4w  = (const float*)d_in[10];
    const float* c4b  = (const float*)d_in[11];
    const float* c5w  = (const float*)d_in[12];
    const float* c5b  = (const float*)d_in[13];
    const float* c6w  = (const float*)d_in[14];
    const float* c6b  = (const float*)d_in[15];
    const float* bn1w = (const float*)d_in[16];
    const float* bn1b = (const float*)d_in[17];
    const float* bn2w = (const float*)d_in[18];
    const float* bn2b = (const float*)d_in[19];

    char* ws = (char*)d_ws;
    float*          xm    = (float*)(ws + 0);                       // 409,600 B
    unsigned short* xT    = (unsigned short*)(ws + 409600);         // 52,428,800 B
    unsigned short* aw    = (unsigned short*)(ws + 52838400);       // 25,165,824 B
    unsigned short* zbuf  = (unsigned short*)(ws + 78004224);       // 52,428,800 B
    float*          stats = (float*)(ws + 130433024);               // 1,024 B
    float*          ss    = (float*)(ws + 130434048);               // 1,024 B

    hipMemsetAsync(xm, 0, 409600, stream);
    hipMemsetAsync(stats, 0, 1024, stream);

    k1_transpose_mean<<<2048, 256, 0, stream>>>(x1, x2, xm, xT);
    k2_adj<<<96, 256, 0, stream>>>(xm, PA, alp, c1w, c1b, c2w, c2b,
                                   c5w, c5b, c6w, c6b, aw);
    k3_main<<<1024, 256, 0, stream>>>(xT, c3w, c3b, c4w, c4b, aw, zbuf, stats);
    k4_finalize<<<1, 128, 0, stream>>>(stats, bn1w, bn1b, bn2w, bn2b, ss);
    k5_apply<<<25600, 256, 0, stream>>>(x1, x2, zbuf, ss, (float*)d_out);
}

// Round 2
// 489.060 us; speedup vs baseline: 1.5971x; 1.5971x over previous
//
#include <hip/hip_runtime.h>

typedef float  f32x4  __attribute__((ext_vector_type(4)));
typedef short  bf16x8 __attribute__((ext_vector_type(8)));
typedef short  s16x4  __attribute__((ext_vector_type(4)));

__device__ __forceinline__ unsigned short f2bf(float f) {
    unsigned int u = __float_as_uint(f);
    unsigned int r = (u + 0x7FFFu + ((u >> 16) & 1u)) >> 16;
    return (unsigned short)r;
}
__device__ __forceinline__ float bf2f(unsigned short h) {
    return __uint_as_float(((unsigned int)h) << 16);
}

// ---------------------------------------------------------------------------
// K3A: fused x-transpose (2-stage LDS) + t-mean partials + conv1x1 via MFMA.
// grid: 2*32*64 blocks (p, n, tc of 4 t's = 100 pos), 256 threads (4 waves).
// Writes X3 rows [ (p*32+n)*64 + c ][ tc*100 + pos ] bf16 into dst0/dst1.
// ---------------------------------------------------------------------------
__global__ __launch_bounds__(256, 4) void k3a_conv(
    const float* __restrict__ x1, const float* __restrict__ x2,
    const float* __restrict__ c3w, const float* __restrict__ c3b,
    const float* __restrict__ c4w, const float* __restrict__ c4b,
    float* __restrict__ xm,
    unsigned short* __restrict__ dst0, unsigned short* __restrict__ dst1,
    int ibase, int ni, int do_means)
{
    const int b  = blockIdx.x;
    const int p  = b >> 11;
    const int n  = (b >> 6) & 31;
    const int tc = b & 63;
    const float* __restrict__ x = p ? x2 : x1;

    __shared__ float tile1[64 * 104];            // fp32 [c][pos(100, pad 104)]
    __shared__ unsigned short tile2[112 * 64];   // bf16 [pos(112)][c swizzled]
    const int tid = threadIdx.x;

    // pass 1: coalesced fp32 load of x[c][tc*100 .. +100)
    const size_t xb = (size_t)n * 409600 + (size_t)tc * 100;
    for (int idx = tid; idx < 1600; idx += 256) {
        const int c = idx / 25, pg = idx % 25;
        *(f32x4*)(tile1 + c * 104 + pg * 4) =
            *(const f32x4*)(x + xb + (size_t)c * 6400 + pg * 4);
    }
    __syncthreads();

    if (do_means) {
        for (int idx = tid; idx < 1600; idx += 256) {
            const int c = idx / 25, v = idx % 25;
            const float* tp = tile1 + c * 104 + v;
            atomicAdd(&xm[((size_t)(p * 32 + n) * 64 + c) * 25 + v],
                      (tp[0] + tp[25] + tp[50] + tp[75]) * (1.0f / 256.0f));
        }
    }

    // pass 2: transpose to channel-last bf16 with 8-group swizzle
    // hw(pos,c) = pos*64 + ((c>>3)^(pos&7))*8 + (c&7)
    for (int idx = tid; idx < 1600; idx += 256) {
        const int pos = idx % 100, cq = idx / 100;
        const float a0 = tile1[(cq * 4 + 0) * 104 + pos];
        const float a1 = tile1[(cq * 4 + 1) * 104 + pos];
        const float a2 = tile1[(cq * 4 + 2) * 104 + pos];
        const float a3 = tile1[(cq * 4 + 3) * 104 + pos];
        const unsigned long long pk =
            (unsigned long long)f2bf(a0)
          | ((unsigned long long)f2bf(a1) << 16)
          | ((unsigned long long)f2bf(a2) << 32)
          | ((unsigned long long)f2bf(a3) << 48);
        const int slot = (cq >> 1) ^ (pos & 7);
        *(unsigned long long*)(tile2 + pos * 64 + slot * 8 + (cq & 1) * 4) = pk;
    }
    if (tid < 192) *(unsigned long long*)(tile2 + 6400 + tid * 4) = 0ull;  // zero pad pos 100..111
    __syncthreads();

    const int w = tid >> 6, lane = tid & 63, q = lane >> 4, m = lane & 15;
    const float* __restrict__ w3 = p ? c4w : c3w;
    const float* __restrict__ b3 = p ? c4b : c3b;

    for (int ii = 0; ii < ni; ii++) {
        const int i = ibase + ii;
        unsigned short* dst = ii ? dst1 : dst0;
        // A-frags: W rows [w*16 .. +16), K=64 in two 32-tiles
        const float* wr = w3 + (size_t)(i * 64 + w * 16 + m) * 64 + q * 8;
        bf16x8 af0, af1;
        {
            const f32x4 w00 = *(const f32x4*)(wr);
            const f32x4 w01 = *(const f32x4*)(wr + 4);
            const f32x4 w10 = *(const f32x4*)(wr + 32);
            const f32x4 w11 = *(const f32x4*)(wr + 36);
            #pragma unroll
            for (int k = 0; k < 4; k++) {
                af0[k] = (short)f2bf(w00[k]); af0[k + 4] = (short)f2bf(w01[k]);
                af1[k] = (short)f2bf(w10[k]); af1[k + 4] = (short)f2bf(w11[k]);
            }
        }
        float bb[4];
        #pragma unroll
        for (int r = 0; r < 4; r++) bb[r] = b3[i * 64 + w * 16 + q * 4 + r];
        const size_t rb = ((size_t)(p * 32 + n) * 64 + w * 16 + q * 4) * 6400
                        + (size_t)tc * 100;
        #pragma unroll
        for (int nt = 0; nt < 7; nt++) {
            const int pos = nt * 16 + m;
            const int slot0 = q ^ (pos & 7);
            const bf16x8 xb0 = *(const bf16x8*)(tile2 + pos * 64 + slot0 * 8);
            const bf16x8 xb1 = *(const bf16x8*)(tile2 + pos * 64 + (slot0 ^ 4) * 8);
            f32x4 d = (f32x4){0.f, 0.f, 0.f, 0.f};
            d = __builtin_amdgcn_mfma_f32_16x16x32_bf16(af0, xb0, d, 0, 0, 0);
            d = __builtin_amdgcn_mfma_f32_16x16x32_bf16(af1, xb1, d, 0, 0, 0);
            if (pos < 100) {
                #pragma unroll
                for (int r = 0; r < 4; r++)
                    dst[rb + (size_t)r * 6400 + pos] = f2bf(d[r] + bb[r]);
            }
        }
    }
}

// ---------------------------------------------------------------------------
// K2: r1/r2 -> rel -> a packed as MFMA B-fragments (bf16, zero-padded)
// grid: 192 blocks (i, n, p), 256 threads
// ---------------------------------------------------------------------------
__global__ void k2_adj(const float* __restrict__ xm,
                       const float* __restrict__ PA, const float* __restrict__ alpha,
                       const float* __restrict__ c1w, const float* __restrict__ c1b,
                       const float* __restrict__ c2w, const float* __restrict__ c2b,
                       const float* __restrict__ c5w, const float* __restrict__ c5b,
                       const float* __restrict__ c6w, const float* __restrict__ c6b,
                       unsigned short* __restrict__ aw)
{
    const int b = blockIdx.x;
    const int i = b >> 6;
    const int n = (b >> 1) & 31;
    const int pp = b & 1;
    __shared__ float xml[3200];
    __shared__ float rl[400];
    __shared__ float rel[5000];
    const int tid = threadIdx.x;

    for (int idx = tid; idx < 3200; idx += 256) {
        const int p_ = idx / 1600, rest = idx % 1600;
        xml[idx] = xm[(size_t)(p_ * 32 + n) * 1600 + rest];
    }
    __syncthreads();

    for (int idx = tid; idx < 400; idx += 256) {
        const int which = idx / 200;
        const int rr = (idx % 200) / 25;
        const int v = idx % 25;
        const float* wv = (which ? c2w : c1w) + (i * 8 + rr) * 64;
        const float* xp = xml + which * 1600;
        float s = (which ? c2b : c1b)[i * 8 + rr];
        for (int c = 0; c < 64; c++) s += wv[c] * xp[c * 25 + v];
        rl[idx] = s;
    }
    __syncthreads();

    for (int idx = tid; idx < 5000; idx += 256) {
        const int r_ = idx / 625;
        const int rem = idx - r_ * 625;
        const int u = rem / 25;
        const int v = rem - u * 25;
        rel[idx] = tanhf(rl[r_ * 25 + u] - rl[200 + r_ * 25 + v]);
    }
    __syncthreads();

    const float al = alpha[0];
    {
        const int p_ = pp;
        const float* w5 = p_ ? c6w : c5w;
        const float* b5 = p_ ? c6b : c5b;
        for (int idx = tid; idx < 8192; idx += 256) {
            const int c = idx >> 7;
            const int ut = (idx >> 6) & 1;
            const int lane = idx & 63;
            const int u = ut * 16 + (lane & 15);
            const int qd = lane >> 4;
            bf16x8 outv;
            if (u < 25) {
                float wrow[8];
                #pragma unroll
                for (int r = 0; r < 8; r++) wrow[r] = w5[(i * 64 + c) * 8 + r];
                const float bias = b5[i * 64 + c];
                #pragma unroll
                for (int j = 0; j < 8; j++) {
                    const int v = qd * 8 + j;
                    float s = 0.f;
                    if (v < 25) {
                        s = bias + (p_ ? al : PA[i * 625 + u * 25 + v]);
                        #pragma unroll
                        for (int r = 0; r < 8; r++) s += rel[r * 625 + u * 25 + v] * wrow[r];
                    }
                    outv[j] = (short)f2bf(s);
                }
            } else {
                #pragma unroll
                for (int j = 0; j < 8; j++) outv[j] = 0;
            }
            *(bf16x8*)(aw + ((size_t)((p_ * 3 + i) * 32 + n) * 64 + c) * 1024
                          + ut * 512 + lane * 8) = outv;
        }
    }
}

// ---------------------------------------------------------------------------
// K3B1: z = X3_0 * a0 + X3_1 * a1 ; z written ALIASED over buf0's own rows.
// grid: 2*32*16 blocks (p, n, cg), wave = one channel c = cg*4 + w.
// ---------------------------------------------------------------------------
__global__ __launch_bounds__(256, 4) void k3b1(
    const unsigned short* __restrict__ aw,
    unsigned short* zb,                       // buf0: A(i=0) source + z dest
    const unsigned short* __restrict__ bufB)  // buf1: A(i=1)
{
    const int b = blockIdx.x;
    const int p = b >> 9;
    const int n = (b >> 4) & 31;
    const int cg = b & 15;
    const int tid = threadIdx.x;
    const int w = tid >> 6, lane = tid & 63, q = lane >> 4, m = lane & 15;
    const int c = cg * 4 + w;

    const size_t row = ((size_t)(p * 32 + n) * 64 + c) * 6400;
    const int aoff = m * 25 + q * 8;

    bf16x8 BA0, BA1, BB0, BB1;
    {
        const size_t a0 = ((size_t)((p * 3 + 0) * 32 + n) * 64 + c) * 1024 + lane * 8;
        const size_t a1 = ((size_t)((p * 3 + 1) * 32 + n) * 64 + c) * 1024 + lane * 8;
        BA0 = *(const bf16x8*)(aw + a0);
        BA1 = *(const bf16x8*)(aw + a0 + 512);
        BB0 = *(const bf16x8*)(aw + a1);
        BB1 = *(const bf16x8*)(aw + a1 + 512);
    }
    unsigned short* zr = zb + row;
    const unsigned short* pA = zb + row + aoff;
    const unsigned short* pB = bufB + row + aoff;

    bf16x8 A0 = *(const bf16x8*)(pA);
    bf16x8 A1 = *(const bf16x8*)(pB);
    for (int tile = 0; tile < 16; tile++) {
        bf16x8 nA0 = A0, nA1 = A1;
        if (tile < 15) {
            nA0 = *(const bf16x8*)(pA + (tile + 1) * 400);
            nA1 = *(const bf16x8*)(pB + (tile + 1) * 400);
        }
        f32x4 u0 = (f32x4){0.f,0.f,0.f,0.f}, u1 = (f32x4){0.f,0.f,0.f,0.f};
        u0 = __builtin_amdgcn_mfma_f32_16x16x32_bf16(A0, BA0, u0, 0, 0, 0);
        u0 = __builtin_amdgcn_mfma_f32_16x16x32_bf16(A1, BB0, u0, 0, 0, 0);
        u1 = __builtin_amdgcn_mfma_f32_16x16x32_bf16(A0, BA1, u1, 0, 0, 0);
        u1 = __builtin_amdgcn_mfma_f32_16x16x32_bf16(A1, BB1, u1, 0, 0, 0);
        #pragma unroll
        for (int r = 0; r < 4; r++) {
            const int o = tile * 400 + (q * 4 + r) * 25;
            zr[o + m] = f2bf(u0[r]);
            if (m < 9) zr[o + 16 + m] = f2bf(u1[r]);
        }
        A0 = nA0; A1 = nA1;
    }
}

// ---------------------------------------------------------------------------
// K3B2: z += X3_2 * a2 (bf16 RMW) + BN sum/sumsq stats.
// ---------------------------------------------------------------------------
__global__ __launch_bounds__(256, 4) void k3b2(
    const unsigned short* __restrict__ aw,
    unsigned short* zb,                       // buf0: z RMW
    const unsigned short* __restrict__ bufB,  // buf1: A(i=2)
    float* __restrict__ stats)
{
    const int b = blockIdx.x;
    const int p = b >> 9;
    const int n = (b >> 4) & 31;
    const int cg = b & 15;
    const int tid = threadIdx.x;
    const int w = tid >> 6, lane = tid & 63, q = lane >> 4, m = lane & 15;
    const int c = cg * 4 + w;

    const size_t row = ((size_t)(p * 32 + n) * 64 + c) * 6400;
    const int aoff = m * 25 + q * 8;

    bf16x8 B0, B1;
    {
        const size_t a2 = ((size_t)((p * 3 + 2) * 32 + n) * 64 + c) * 1024 + lane * 8;
        B0 = *(const bf16x8*)(aw + a2);
        B1 = *(const bf16x8*)(aw + a2 + 512);
    }
    unsigned short* zr = zb + row;
    const unsigned short* pB = bufB + row + aoff;

    float sum = 0.f, ssq = 0.f;
    bf16x8 A2 = *(const bf16x8*)(pB);
    for (int tile = 0; tile < 16; tile++) {
        bf16x8 nA2 = A2;
        if (tile < 15) nA2 = *(const bf16x8*)(pB + (tile + 1) * 400);
        f32x4 u0 = (f32x4){0.f,0.f,0.f,0.f}, u1 = (f32x4){0.f,0.f,0.f,0.f};
        u0 = __builtin_amdgcn_mfma_f32_16x16x32_bf16(A2, B0, u0, 0, 0, 0);
        u1 = __builtin_amdgcn_mfma_f32_16x16x32_bf16(A2, B1, u1, 0, 0, 0);
        #pragma unroll
        for (int r = 0; r < 4; r++) {
            const int o = tile * 400 + (q * 4 + r) * 25;
            const float v0 = u0[r] + bf2f(zr[o + m]);
            zr[o + m] = f2bf(v0); sum += v0; ssq += v0 * v0;
            if (m < 9) {
                const float v1 = u1[r] + bf2f(zr[o + 16 + m]);
                zr[o + 16 + m] = f2bf(v1); sum += v1; ssq += v1 * v1;
            }
        }
        A2 = nA2;
    }
    #pragma unroll
    for (int off = 32; off > 0; off >>= 1) {
        sum += __shfl_xor(sum, off, 64);
        ssq += __shfl_xor(ssq, off, 64);
    }
    if (lane == 0) {
        atomicAdd(&stats[(p * 64 + c) * 2 + 0], sum);
        atomicAdd(&stats[(p * 64 + c) * 2 + 1], ssq);
    }
}

// ---------------------------------------------------------------------------
// K4: BN stats -> per-channel scale/shift
// ---------------------------------------------------------------------------
__global__ void k4_finalize(const float* __restrict__ stats,
                            const float* __restrict__ bn1w, const float* __restrict__ bn1b,
                            const float* __restrict__ bn2w, const float* __restrict__ bn2b,
                            float* __restrict__ ss)
{
    const int tid = threadIdx.x;
    if (tid < 128) {
        const int p = tid >> 6, c = tid & 63;
        const float cnt = 204800.f;   // N*T*V
        const float mean = stats[tid * 2] / cnt;
        const float var  = stats[tid * 2 + 1] / cnt - mean * mean;
        const float gw = p ? bn2w[c] : bn1w[c];
        const float gb = p ? bn2b[c] : bn1b[c];
        const float scale = gw * rsqrtf(var + 1e-5f);
        ss[tid * 2]     = scale;
        ss[tid * 2 + 1] = gb - mean * scale;
    }
}

// ---------------------------------------------------------------------------
// K5: y = relu(z*scale + shift + x), float4-wide  (z = buf0, same geometry)
// ---------------------------------------------------------------------------
__global__ void k5_apply(const float* __restrict__ x1, const float* __restrict__ x2,
                         const unsigned short* __restrict__ z, const float* __restrict__ ss,
                         float* __restrict__ out)
{
    const size_t g = (size_t)blockIdx.x * 256 + threadIdx.x;
    const size_t e = g * 4;
    const int p = (int)(e / 13107200u);
    const int c = (int)((e / 6400u) & 63);
    const float* xsrc = p ? x2 : x1;
    const f32x4 xv = *(const f32x4*)(xsrc + (e - (size_t)p * 13107200u));
    const s16x4 zv = *(const s16x4*)(const void*)(z + e);
    const float scale = ss[(p * 64 + c) * 2];
    const float shift = ss[(p * 64 + c) * 2 + 1];
    f32x4 o;
    #pragma unroll
    for (int k = 0; k < 4; k++) {
        const float zf = bf2f((unsigned short)zv[k]);
        const float y = zf * scale + shift + xv[k];
        o[k] = y > 0.f ? y : 0.f;
    }
    *(f32x4*)(out + e) = o;
}

// ---------------------------------------------------------------------------
extern "C" void kernel_launch(void* const* d_in, const int* in_sizes, int n_in,
                              void* d_out, int out_size, void* d_ws, size_t ws_size,
                              hipStream_t stream)
{
    (void)in_sizes; (void)n_in; (void)out_size; (void)ws_size;
    const float* x1   = (const float*)d_in[0];
    const float* x2   = (const float*)d_in[1];
    const float* PA   = (const float*)d_in[2];
    const float* alp  = (const float*)d_in[3];
    const float* c1w  = (const float*)d_in[4];
    const float* c1b  = (const float*)d_in[5];
    const float* c2w  = (const float*)d_in[6];
    const float* c2b  = (const float*)d_in[7];
    const float* c3w  = (const float*)d_in[8];
    const float* c3b  = (const float*)d_in[9];
    const float* c4w  = (const float*)d_in[10];
    const float* c4b  = (const float*)d_in[11];
    const float* c5w  = (const float*)d_in[12];
    const float* c5b  = (const float*)d_in[13];
    const float* c6w  = (const float*)d_in[14];
    const float* c6b  = (const float*)d_in[15];
    const float* bn1w = (const float*)d_in[16];
    const float* bn1b = (const float*)d_in[17];
    const float* bn2w = (const float*)d_in[18];
    const float* bn2b = (const float*)d_in[19];

    char* ws = (char*)d_ws;
    float*          xm    = (float*)(ws + 0);                     //    409,600 B
    unsigned short* aw    = (unsigned short*)(ws + 409600);       // 25,165,824 B
    unsigned short* buf0  = (unsigned short*)(ws + 25575424);     // 52,428,800 B
    unsigned short* buf1  = (unsigned short*)(ws + 78004224);     // 52,428,800 B
    float*          stats = (float*)(ws + 130433024);             //      1,024 B
    float*          ss    = (float*)(ws + 130434048);             //      1,024 B
    // total 130,435,072 B == round-1 footprint (known to fit)

    hipMemsetAsync(xm, 0, 409600, stream);
    hipMemsetAsync(stats, 0, 1024, stream);

    // subsets 0,1 -> buf0,buf1 (+ means)
    k3a_conv<<<4096, 256, 0, stream>>>(x1, x2, c3w, c3b, c4w, c4b,
                                       xm, buf0, buf1, 0, 2, 1);
    k2_adj<<<192, 256, 0, stream>>>(xm, PA, alp, c1w, c1b, c2w, c2b,
                                    c5w, c5b, c6w, c6b, aw);
    // z(i0+i1) written over buf0's own rows
    k3b1<<<1024, 256, 0, stream>>>(aw, buf0, buf1);
    // subset 2 -> buf1 (buf1 dead after k3b1; no means)
    k3a_conv<<<4096, 256, 0, stream>>>(x1, x2, c3w, c3b, c4w, c4b,
                                       xm, buf1, buf1, 2, 1, 0);
    // z += i2 contribution (bf16 RMW) + stats
    k3b2<<<1024, 256, 0, stream>>>(aw, buf0, buf1, stats);
    k4_finalize<<<1, 128, 0, stream>>>(stats, bn1w, bn1b, bn2w, bn2b, ss);
    k5_apply<<<25600, 256, 0, stream>>>(x1, x2, buf0, ss, (float*)d_out);
}